// Round 15
// baseline (107.795 us; speedup 1.0000x reference)
//
#include <hip/hip_runtime.h>

// DiffuseLR v13: 6 plain kernels, NO in-graph memset (suspected ~40us/replay).
//   fcT'[n][c] = dinv[n]*fc_w[c][n]
//   gT[s][c]   = dinv[s]*(sum_{e:src=s} w_e*fcT'[dst_e][c] + fcT'[s][c])
//   logits = x @ gT + b; out = softmax(logits)

#define N_NODES   20000
#define N_EDGES_C 640000
#define N_CLASSES 30
#define CPAD      32

// deg-hist geometry
#define HBLKS     32
#define HNODES    10000
#define HEDGES    (N_EDGES_C / HBLKS)     // 20000

// partition geometry
#define BN        32
#define NB        625                     // 20000/32 exactly
#define NSLAB     500
#define SLAB_E    (N_EDGES_C / NSLAB)     // 1280 (div by 4)
#define ECAP      1440                    // mean 1024, sd ~32 -> 13 sigma margin

// fused fold+gemm geometry
#define XLD       129                     // xl[n][b] stride -> conflict-free
#define GTLD      33                      // gt[c][n] stride

// K0: zero gcur (replaces hipMemsetAsync — in-graph fills measured ~40us).
__global__ void k0_init(int* __restrict__ gcur) {
    int t = threadIdx.x;
    if (t < NB) gcur[t] = 0;
}

// K1: blocks [0,64): weighted in-degree LDS histogram per (edge-slab, half);
//     blocks [64,564): scatter slab into fixed-capacity buckets (raw w).
__global__ __launch_bounds__(512) void k1_histscatter(const int* __restrict__ src,
        const int* __restrict__ dst, const float* __restrict__ ew,
        float* __restrict__ degp, int* __restrict__ gcur,
        int2* __restrict__ erec) {
    __shared__ union {
        float h[HNODES];                                               // 40 KB
        struct { int ssrc[SLAB_E]; int shist[NB]; int scur[NB]; } s;   // 10.1 KB
    } sm;
    int bid = blockIdx.x;
    int t = threadIdx.x;
    if (bid < 2 * HBLKS) {
        // ---- deg-hist role ----
        int eb = bid >> 1, half = bid & 1;
        int nbase = half * HNODES;
        for (int i = t; i < HNODES; i += 512) sm.h[i] = 0.f;
        __syncthreads();
        const int4* d4 = (const int4*)(dst + eb * HEDGES);
        const float4* w4 = (const float4*)(ew + eb * HEDGES);
        for (int i = t; i < HEDGES / 4; i += 512) {
            int4 dv = d4[i]; float4 wv = w4[i];
            unsigned r;
            r = (unsigned)(dv.x - nbase); if (r < HNODES) atomicAdd(&sm.h[r], wv.x);
            r = (unsigned)(dv.y - nbase); if (r < HNODES) atomicAdd(&sm.h[r], wv.y);
            r = (unsigned)(dv.z - nbase); if (r < HNODES) atomicAdd(&sm.h[r], wv.z);
            r = (unsigned)(dv.w - nbase); if (r < HNODES) atomicAdd(&sm.h[r], wv.w);
        }
        __syncthreads();
        float* outp = degp + (size_t)bid * HNODES;
        for (int i = t; i < HNODES; i += 512) outp[i] = sm.h[i];
    } else {
        // ---- scatter role ----
        int slab = bid - 2 * HBLKS;
        int e0 = slab * SLAB_E;
        for (int i = t; i < NB; i += 512) sm.s.shist[i] = 0;
        __syncthreads();
        const int4* s4 = (const int4*)(src + e0);
        for (int i = t; i < SLAB_E / 4; i += 512) {
            int4 sv = s4[i];
            ((int4*)sm.s.ssrc)[i] = sv;
            atomicAdd(&sm.s.shist[sv.x >> 5], 1);
            atomicAdd(&sm.s.shist[sv.y >> 5], 1);
            atomicAdd(&sm.s.shist[sv.z >> 5], 1);
            atomicAdd(&sm.s.shist[sv.w >> 5], 1);
        }
        __syncthreads();
        for (int b = t; b < NB; b += 512)
            sm.s.scur[b] = b * ECAP + atomicAdd(&gcur[b], sm.s.shist[b]);
        __syncthreads();
        const int4* d4 = (const int4*)(dst + e0);
        const float4* w4 = (const float4*)(ew + e0);
        for (int i = t; i < SLAB_E / 4; i += 512) {
            int4 dv = d4[i]; float4 wv = w4[i];
            int4 sv = ((const int4*)sm.s.ssrc)[i];
            int s, p;
            s = sv.x; p = atomicAdd(&sm.s.scur[s >> 5], 1);
            erec[p] = make_int2(((s & 31) << 15) | dv.x, __float_as_int(wv.x));
            s = sv.y; p = atomicAdd(&sm.s.scur[s >> 5], 1);
            erec[p] = make_int2(((s & 31) << 15) | dv.y, __float_as_int(wv.y));
            s = sv.z; p = atomicAdd(&sm.s.scur[s >> 5], 1);
            erec[p] = make_int2(((s & 31) << 15) | dv.z, __float_as_int(wv.z));
            s = sv.w; p = atomicAdd(&sm.s.scur[s >> 5], 1);
            erec[p] = make_int2(((s & 31) << 15) | dv.w, __float_as_int(wv.w));
        }
    }
}

// K2: per 32-node bucket: dinv from the 64 slab-partials + pre-scaled transpose
// fcT'[n][c] = dinv[n]*fc_w[c][n] (all global accesses coalesced).
__global__ __launch_bounds__(256) void k2_prep(const float* __restrict__ degp,
        const float* __restrict__ fc_w, float* __restrict__ dinv,
        float* __restrict__ fcT) {
    __shared__ float tile[CPAD][BN + 1];
    __shared__ float sdinv[BN];
    int n0 = blockIdx.x * BN;
    int t = threadIdx.x;
    if (t < BN) {
        int n = n0 + t;
        int half = n / HNODES, nn = n - half * HNODES;
        float s = 1.0f;   // self-loop weight
        for (int eb = 0; eb < HBLKS; eb++)
            s += degp[(size_t)((eb << 1) | half) * HNODES + nn];
        float di = rsqrtf(s);
        dinv[n] = di;
        sdinv[t] = di;
    }
    #pragma unroll
    for (int k = 0; k < 4; k++) {
        int idx = k * 256 + t;
        int c = idx >> 5, nn = idx & 31;
        tile[c][nn] = (c < N_CLASSES) ? fc_w[c * N_NODES + n0 + nn] : 0.f;
    }
    __syncthreads();
    #pragma unroll
    for (int k = 0; k < 4; k++) {
        int idx = k * 256 + t;
        int nn = idx >> 5, c = idx & 31;
        fcT[(size_t)(n0 + nn) * CPAD + c] = sdinv[nn] * tile[c][nn];
    }
}

// K3: fused fold+GEMM per 32-node bucket. Row-walk unrolled x4 (independent
// L2 load chains). part layout: [c][bucket][b] for coalesced reduction.
__global__ __launch_bounds__(512) void k3_foldgemm(const int2* __restrict__ erec,
        const int* __restrict__ gcur, const float* __restrict__ dinv,
        const float* __restrict__ fcT, const float* __restrict__ x,
        float* __restrict__ part) {
    __shared__ union {
        struct { int2 srt[ECAP]; int hist[BN]; int rowst[BN]; int cur[BN]; } f; // 11904 B
        struct { float xl[BN * XLD]; float gt[CPAD * GTLD]; } g;                // 20736 B
    } sm;
    float* gt = sm.g.gt;   // offset 16512 > 11904: disjoint from f during fold
    int bucket = blockIdx.x;
    int t = threadIdx.x;
    int nlo = bucket * BN;
    int bstart = bucket * ECAP;
    int len = min(gcur[bucket], ECAP);

    // ---- counting sort by node ----
    if (t < BN) sm.f.hist[t] = 0;
    __syncthreads();
    for (int i = t; i < len; i += 512)
        atomicAdd(&sm.f.hist[((unsigned)erec[bstart + i].x) >> 15], 1);
    __syncthreads();
    if (t < BN) {
        int h = sm.f.hist[t];
        int v = h;
        #pragma unroll
        for (int o = 1; o < BN; o <<= 1) {
            int u = __shfl_up(v, o, BN);
            if (t >= o) v += u;
        }
        sm.f.rowst[t] = v - h;
        sm.f.cur[t]   = v - h;
    }
    __syncthreads();
    for (int i = t; i < len; i += 512) {
        int2 r = erec[bstart + i];
        int p = atomicAdd(&sm.f.cur[((unsigned)r.x) >> 15], 1);
        sm.f.srt[p] = r;
    }
    __syncthreads();

    // ---- register gather (ILP4) -> gt tile ----
    int c = t & 31;
    int grp = t >> 5;                    // 0..15; nodes grp, grp+16
    #pragma unroll
    for (int half = 0; half < 2; half++) {
        int nn = grp + half * 16;
        int n = nlo + nn;
        float a0 = fcT[(size_t)n * CPAD + c];   // self-loop (pre-scaled)
        float a1 = 0.f, a2 = 0.f, a3 = 0.f;
        int i = sm.f.rowst[nn], re = i + sm.f.hist[nn];
        for (; i + 3 < re; i += 4) {
            int2 r0 = sm.f.srt[i], r1 = sm.f.srt[i + 1];
            int2 r2 = sm.f.srt[i + 2], r3 = sm.f.srt[i + 3];
            a0 += __int_as_float(r0.y) * fcT[(size_t)(r0.x & 0x7FFF) * CPAD + c];
            a1 += __int_as_float(r1.y) * fcT[(size_t)(r1.x & 0x7FFF) * CPAD + c];
            a2 += __int_as_float(r2.y) * fcT[(size_t)(r2.x & 0x7FFF) * CPAD + c];
            a3 += __int_as_float(r3.y) * fcT[(size_t)(r3.x & 0x7FFF) * CPAD + c];
        }
        for (; i < re; i++) {
            int2 r0 = sm.f.srt[i];
            a0 += __int_as_float(r0.y) * fcT[(size_t)(r0.x & 0x7FFF) * CPAD + c];
        }
        gt[c * GTLD + nn] = dinv[n] * ((a0 + a1) + (a2 + a3));
    }
    __syncthreads();   // gt complete; f region dead

    // ---- gemm: stage x[128][32-chunk] transposed to xl[n][b] ----
    for (int o = t; o < 128 * BN; o += 512) {
        int b = o >> 5, n = o & 31;
        sm.g.xl[n * XLD + b] = x[(size_t)b * N_NODES + nlo + n];
    }
    __syncthreads();

    int wv = t >> 6, l = t & 63;   // wave = class group, lane = batch
    float a00 = 0.f, a01 = 0.f, a10 = 0.f, a11 = 0.f;
    float a20 = 0.f, a21 = 0.f, a30 = 0.f, a31 = 0.f;
    #pragma unroll 8
    for (int n = 0; n < BN; n++) {
        float x0 = sm.g.xl[n * XLD + l];
        float x1 = sm.g.xl[n * XLD + 64 + l];
        float g0 = gt[(wv)      * GTLD + n];   // wave-uniform broadcast
        float g1 = gt[(wv +  8) * GTLD + n];
        float g2 = gt[(wv + 16) * GTLD + n];
        float g3 = gt[(wv + 24) * GTLD + n];
        a00 += x0 * g0; a01 += x1 * g0;
        a10 += x0 * g1; a11 += x1 * g1;
        a20 += x0 * g2; a21 += x1 * g2;
        a30 += x0 * g3; a31 += x1 * g3;
    }
    // part[c][bucket][b]
    part[((size_t)(wv)      * NB + bucket) * 128 + l]      = a00;
    part[((size_t)(wv)      * NB + bucket) * 128 + 64 + l] = a01;
    part[((size_t)(wv +  8) * NB + bucket) * 128 + l]      = a10;
    part[((size_t)(wv +  8) * NB + bucket) * 128 + 64 + l] = a11;
    part[((size_t)(wv + 16) * NB + bucket) * 128 + l]      = a20;
    part[((size_t)(wv + 16) * NB + bucket) * 128 + 64 + l] = a21;
    part[((size_t)(wv + 24) * NB + bucket) * 128 + l]      = a30;
    part[((size_t)(wv + 24) * NB + bucket) * 128 + 64 + l] = a31;
}

// K4: per-class full reduction + bias: logits[b][c] = sum_ch part[c][ch][b]+b_c
__global__ __launch_bounds__(128) void k4_lred(const float* __restrict__ part,
        const float* __restrict__ fc_b, float* __restrict__ logits_g) {
    int c = blockIdx.x;
    int b = threadIdx.x;
    const float* p = part + (size_t)c * NB * 128 + b;
    float s = 0.f;
    #pragma unroll 8
    for (int ch = 0; ch < NB; ch++)
        s += p[(size_t)ch * 128];       // 128 lanes -> 512B coalesced per ch
    logits_g[b * CPAD + c] = s + fc_b[c];
}

// K5: softmax
__global__ void k5_smax(const float* __restrict__ logits_g,
        float* __restrict__ out) {
    int b = threadIdx.x;
    float v[N_CLASSES], m = -1e30f;
    #pragma unroll
    for (int c = 0; c < N_CLASSES; c++) {
        v[c] = logits_g[b * CPAD + c];
        m = fmaxf(m, v[c]);
    }
    float s = 0.f;
    #pragma unroll
    for (int c = 0; c < N_CLASSES; c++) { v[c] = __expf(v[c] - m); s += v[c]; }
    float inv = 1.0f / s;
    #pragma unroll
    for (int c = 0; c < N_CLASSES; c++) out[b * N_CLASSES + c] = v[c] * inv;
}

extern "C" void kernel_launch(void* const* d_in, const int* in_sizes, int n_in,
                              void* d_out, int out_size, void* d_ws, size_t ws_size,
                              hipStream_t stream) {
    const float* x          = (const float*)d_in[0];
    const int*   edge_index = (const int*)d_in[1];
    const float* ew         = (const float*)d_in[2];
    const float* fc_w       = (const float*)d_in[3];
    const float* fc_b       = (const float*)d_in[4];
    float* out = (float*)d_out;

    const int* src = edge_index;
    const int* dst = edge_index + N_EDGES_C;

    // ws layout (float slots), time-disjoint aliasing:
    //   A (2,560,000): degp [K1..K2] (640,000) -> part [K3..K4]
    float* A        = (float*)d_ws;                          // 2,560,000
    int2*  erec     = (int2*)(A + (size_t)NB * CPAD * 128);  // 900,000 int2
    float* dinv     = (float*)(erec + (size_t)NB * ECAP);    // 20,000
    int*   gcur     = (int*)(dinv + N_NODES);                // 625 (pad 640)
    float* fcT      = (float*)(gcur + 640);                  // 640,000
    float* logits_g = fcT + (size_t)N_NODES * CPAD;          // 4,096

    float* degp = A;
    float* part = A;

    k0_init<<<1, 640, 0, stream>>>(gcur);
    k1_histscatter<<<2 * HBLKS + NSLAB, 512, 0, stream>>>(src, dst, ew, degp,
                                                          gcur, erec);
    k2_prep<<<NB, 256, 0, stream>>>(degp, fc_w, dinv, fcT);
    k3_foldgemm<<<NB, 512, 0, stream>>>(erec, gcur, dinv, fcT, x, part);
    k4_lred<<<N_CLASSES, 128, 0, stream>>>(part, fc_b, logits_g);
    k5_smax<<<1, 128, 0, stream>>>(logits_g, out);
}

// Round 16
// 94.562 us; speedup vs baseline: 1.1399x; 1.1399x over previous
//
#include <hip/hip_runtime.h>

// DiffuseLR v14: 6 plain kernels, no in-graph memset (confirmed ~40us/replay),
// split-quarter logits reduction (R15's 30-block lred was a 44us serial tail).
//   fcT'[n][c] = dinv[n]*fc_w[c][n]
//   gT[s][c]   = dinv[s]*(sum_{e:src=s} w_e*fcT'[dst_e][c] + fcT'[s][c])
//   logits = x @ gT + b; out = softmax(logits)

#define N_NODES   20000
#define N_EDGES_C 640000
#define N_CLASSES 30
#define CPAD      32

// deg-hist geometry
#define HBLKS     32
#define HNODES    10000
#define HEDGES    (N_EDGES_C / HBLKS)     // 20000

// partition geometry
#define BN        32
#define NB        625                     // 20000/32 exactly
#define NSLAB     500
#define SLAB_E    (N_EDGES_C / NSLAB)     // 1280 (div by 4)
#define ECAP      1440                    // mean 1024, sd ~32 -> 13 sigma margin

// fused fold+gemm geometry
#define XLD       129                     // xl[n][b] stride -> conflict-free
#define GTLD      33                      // gt[c][n] stride

#define NQ        16                      // lred quarters

// K0: zero gcur (replaces hipMemsetAsync)
__global__ void k0_init(int* __restrict__ gcur) {
    int t = threadIdx.x;
    if (t < NB) gcur[t] = 0;
}

// K1: blocks [0,64): weighted in-degree LDS histogram per (edge-slab, half);
//     blocks [64,564): scatter slab into fixed-capacity buckets (raw w).
__global__ __launch_bounds__(512) void k1_histscatter(const int* __restrict__ src,
        const int* __restrict__ dst, const float* __restrict__ ew,
        float* __restrict__ degp, int* __restrict__ gcur,
        int2* __restrict__ erec) {
    __shared__ union {
        float h[HNODES];                                               // 40 KB
        struct { int ssrc[SLAB_E]; int shist[NB]; int scur[NB]; } s;   // 10.1 KB
    } sm;
    int bid = blockIdx.x;
    int t = threadIdx.x;
    if (bid < 2 * HBLKS) {
        // ---- deg-hist role ----
        int eb = bid >> 1, half = bid & 1;
        int nbase = half * HNODES;
        for (int i = t; i < HNODES; i += 512) sm.h[i] = 0.f;
        __syncthreads();
        const int4* d4 = (const int4*)(dst + eb * HEDGES);
        const float4* w4 = (const float4*)(ew + eb * HEDGES);
        for (int i = t; i < HEDGES / 4; i += 512) {
            int4 dv = d4[i]; float4 wv = w4[i];
            unsigned r;
            r = (unsigned)(dv.x - nbase); if (r < HNODES) atomicAdd(&sm.h[r], wv.x);
            r = (unsigned)(dv.y - nbase); if (r < HNODES) atomicAdd(&sm.h[r], wv.y);
            r = (unsigned)(dv.z - nbase); if (r < HNODES) atomicAdd(&sm.h[r], wv.z);
            r = (unsigned)(dv.w - nbase); if (r < HNODES) atomicAdd(&sm.h[r], wv.w);
        }
        __syncthreads();
        float* outp = degp + (size_t)bid * HNODES;
        for (int i = t; i < HNODES; i += 512) outp[i] = sm.h[i];
    } else {
        // ---- scatter role ----
        int slab = bid - 2 * HBLKS;
        int e0 = slab * SLAB_E;
        for (int i = t; i < NB; i += 512) sm.s.shist[i] = 0;
        __syncthreads();
        const int4* s4 = (const int4*)(src + e0);
        for (int i = t; i < SLAB_E / 4; i += 512) {
            int4 sv = s4[i];
            ((int4*)sm.s.ssrc)[i] = sv;
            atomicAdd(&sm.s.shist[sv.x >> 5], 1);
            atomicAdd(&sm.s.shist[sv.y >> 5], 1);
            atomicAdd(&sm.s.shist[sv.z >> 5], 1);
            atomicAdd(&sm.s.shist[sv.w >> 5], 1);
        }
        __syncthreads();
        for (int b = t; b < NB; b += 512)
            sm.s.scur[b] = b * ECAP + atomicAdd(&gcur[b], sm.s.shist[b]);
        __syncthreads();
        const int4* d4 = (const int4*)(dst + e0);
        const float4* w4 = (const float4*)(ew + e0);
        for (int i = t; i < SLAB_E / 4; i += 512) {
            int4 dv = d4[i]; float4 wv = w4[i];
            int4 sv = ((const int4*)sm.s.ssrc)[i];
            int s, p;
            s = sv.x; p = atomicAdd(&sm.s.scur[s >> 5], 1);
            erec[p] = make_int2(((s & 31) << 15) | dv.x, __float_as_int(wv.x));
            s = sv.y; p = atomicAdd(&sm.s.scur[s >> 5], 1);
            erec[p] = make_int2(((s & 31) << 15) | dv.y, __float_as_int(wv.y));
            s = sv.z; p = atomicAdd(&sm.s.scur[s >> 5], 1);
            erec[p] = make_int2(((s & 31) << 15) | dv.z, __float_as_int(wv.z));
            s = sv.w; p = atomicAdd(&sm.s.scur[s >> 5], 1);
            erec[p] = make_int2(((s & 31) << 15) | dv.w, __float_as_int(wv.w));
        }
    }
}

// K2: per 32-node bucket: dinv from the 64 slab-partials + pre-scaled transpose
__global__ __launch_bounds__(256) void k2_prep(const float* __restrict__ degp,
        const float* __restrict__ fc_w, float* __restrict__ dinv,
        float* __restrict__ fcT) {
    __shared__ float tile[CPAD][BN + 1];
    __shared__ float sdinv[BN];
    int n0 = blockIdx.x * BN;
    int t = threadIdx.x;
    if (t < BN) {
        int n = n0 + t;
        int half = n / HNODES, nn = n - half * HNODES;
        float s = 1.0f;   // self-loop weight
        for (int eb = 0; eb < HBLKS; eb++)
            s += degp[(size_t)((eb << 1) | half) * HNODES + nn];
        float di = rsqrtf(s);
        dinv[n] = di;
        sdinv[t] = di;
    }
    #pragma unroll
    for (int k = 0; k < 4; k++) {
        int idx = k * 256 + t;
        int c = idx >> 5, nn = idx & 31;
        tile[c][nn] = (c < N_CLASSES) ? fc_w[c * N_NODES + n0 + nn] : 0.f;
    }
    __syncthreads();
    #pragma unroll
    for (int k = 0; k < 4; k++) {
        int idx = k * 256 + t;
        int nn = idx >> 5, c = idx & 31;
        fcT[(size_t)(n0 + nn) * CPAD + c] = sdinv[nn] * tile[c][nn];
    }
}

// K3: fused fold+GEMM per 32-node bucket (R15, ILP4 row-walk).
// part layout: [c][bucket][b].
__global__ __launch_bounds__(512) void k3_foldgemm(const int2* __restrict__ erec,
        const int* __restrict__ gcur, const float* __restrict__ dinv,
        const float* __restrict__ fcT, const float* __restrict__ x,
        float* __restrict__ part) {
    __shared__ union {
        struct { int2 srt[ECAP]; int hist[BN]; int rowst[BN]; int cur[BN]; } f; // 11904 B
        struct { float xl[BN * XLD]; float gt[CPAD * GTLD]; } g;                // 20736 B
    } sm;
    float* gt = sm.g.gt;   // offset 16512 > 11904: disjoint from f during fold
    int bucket = blockIdx.x;
    int t = threadIdx.x;
    int nlo = bucket * BN;
    int bstart = bucket * ECAP;
    int len = min(gcur[bucket], ECAP);

    if (t < BN) sm.f.hist[t] = 0;
    __syncthreads();
    for (int i = t; i < len; i += 512)
        atomicAdd(&sm.f.hist[((unsigned)erec[bstart + i].x) >> 15], 1);
    __syncthreads();
    if (t < BN) {
        int h = sm.f.hist[t];
        int v = h;
        #pragma unroll
        for (int o = 1; o < BN; o <<= 1) {
            int u = __shfl_up(v, o, BN);
            if (t >= o) v += u;
        }
        sm.f.rowst[t] = v - h;
        sm.f.cur[t]   = v - h;
    }
    __syncthreads();
    for (int i = t; i < len; i += 512) {
        int2 r = erec[bstart + i];
        int p = atomicAdd(&sm.f.cur[((unsigned)r.x) >> 15], 1);
        sm.f.srt[p] = r;
    }
    __syncthreads();

    int c = t & 31;
    int grp = t >> 5;                    // 0..15; nodes grp, grp+16
    #pragma unroll
    for (int half = 0; half < 2; half++) {
        int nn = grp + half * 16;
        int n = nlo + nn;
        float a0 = fcT[(size_t)n * CPAD + c];   // self-loop (pre-scaled)
        float a1 = 0.f, a2 = 0.f, a3 = 0.f;
        int i = sm.f.rowst[nn], re = i + sm.f.hist[nn];
        for (; i + 3 < re; i += 4) {
            int2 r0 = sm.f.srt[i], r1 = sm.f.srt[i + 1];
            int2 r2 = sm.f.srt[i + 2], r3 = sm.f.srt[i + 3];
            a0 += __int_as_float(r0.y) * fcT[(size_t)(r0.x & 0x7FFF) * CPAD + c];
            a1 += __int_as_float(r1.y) * fcT[(size_t)(r1.x & 0x7FFF) * CPAD + c];
            a2 += __int_as_float(r2.y) * fcT[(size_t)(r2.x & 0x7FFF) * CPAD + c];
            a3 += __int_as_float(r3.y) * fcT[(size_t)(r3.x & 0x7FFF) * CPAD + c];
        }
        for (; i < re; i++) {
            int2 r0 = sm.f.srt[i];
            a0 += __int_as_float(r0.y) * fcT[(size_t)(r0.x & 0x7FFF) * CPAD + c];
        }
        gt[c * GTLD + nn] = dinv[n] * ((a0 + a1) + (a2 + a3));
    }
    __syncthreads();   // gt complete; f region dead

    for (int o = t; o < 128 * BN; o += 512) {
        int b = o >> 5, n = o & 31;
        sm.g.xl[n * XLD + b] = x[(size_t)b * N_NODES + nlo + n];
    }
    __syncthreads();

    int wv = t >> 6, l = t & 63;   // wave = class group, lane = batch
    float a00 = 0.f, a01 = 0.f, a10 = 0.f, a11 = 0.f;
    float a20 = 0.f, a21 = 0.f, a30 = 0.f, a31 = 0.f;
    #pragma unroll 8
    for (int n = 0; n < BN; n++) {
        float x0 = sm.g.xl[n * XLD + l];
        float x1 = sm.g.xl[n * XLD + 64 + l];
        float g0 = gt[(wv)      * GTLD + n];   // wave-uniform broadcast
        float g1 = gt[(wv +  8) * GTLD + n];
        float g2 = gt[(wv + 16) * GTLD + n];
        float g3 = gt[(wv + 24) * GTLD + n];
        a00 += x0 * g0; a01 += x1 * g0;
        a10 += x0 * g1; a11 += x1 * g1;
        a20 += x0 * g2; a21 += x1 * g2;
        a30 += x0 * g3; a31 += x1 * g3;
    }
    part[((size_t)(wv)      * NB + bucket) * 128 + l]      = a00;
    part[((size_t)(wv)      * NB + bucket) * 128 + 64 + l] = a01;
    part[((size_t)(wv +  8) * NB + bucket) * 128 + l]      = a10;
    part[((size_t)(wv +  8) * NB + bucket) * 128 + 64 + l] = a11;
    part[((size_t)(wv + 16) * NB + bucket) * 128 + l]      = a20;
    part[((size_t)(wv + 16) * NB + bucket) * 128 + 64 + l] = a21;
    part[((size_t)(wv + 24) * NB + bucket) * 128 + l]      = a30;
    part[((size_t)(wv + 24) * NB + bucket) * 128 + 64 + l] = a31;
}

// K4: split-quarter reduction: lpart[q][c][b] = sum_{ch ≡ q mod NQ} part[c][ch][b]
// Grid (30, 16) = 480 blocks -> real occupancy; ~40 coalesced 512B lines each.
__global__ __launch_bounds__(128) void k4_lred(const float* __restrict__ part,
        float* __restrict__ lpart) {
    int c = blockIdx.x, q = blockIdx.y;
    int b = threadIdx.x;
    const float* p = part + (size_t)c * NB * 128 + b;
    float s = 0.f;
    for (int ch = q; ch < NB; ch += NQ)
        s += p[(size_t)ch * 128];
    lpart[((size_t)q * CPAD + c) * 128 + b] = s;
}

// K5: final sum over quarters + bias + softmax
__global__ void k5_smax(const float* __restrict__ lpart,
        const float* __restrict__ fc_b, float* __restrict__ out) {
    int b = threadIdx.x;
    float v[N_CLASSES], m = -1e30f;
    #pragma unroll
    for (int c = 0; c < N_CLASSES; c++) {
        float s = fc_b[c];
        #pragma unroll
        for (int q = 0; q < NQ; q++) s += lpart[((size_t)q * CPAD + c) * 128 + b];
        v[c] = s; m = fmaxf(m, s);
    }
    float s = 0.f;
    #pragma unroll
    for (int c = 0; c < N_CLASSES; c++) { v[c] = __expf(v[c] - m); s += v[c]; }
    float inv = 1.0f / s;
    #pragma unroll
    for (int c = 0; c < N_CLASSES; c++) out[b * N_CLASSES + c] = v[c] * inv;
}

extern "C" void kernel_launch(void* const* d_in, const int* in_sizes, int n_in,
                              void* d_out, int out_size, void* d_ws, size_t ws_size,
                              hipStream_t stream) {
    const float* x          = (const float*)d_in[0];
    const int*   edge_index = (const int*)d_in[1];
    const float* ew         = (const float*)d_in[2];
    const float* fc_w       = (const float*)d_in[3];
    const float* fc_b       = (const float*)d_in[4];
    float* out = (float*)d_out;

    const int* src = edge_index;
    const int* dst = edge_index + N_EDGES_C;

    // ws layout (float slots), time-disjoint aliasing:
    //   A (2,560,000): degp [K1..K2] (640,000) -> part [K3..K4]
    float* A     = (float*)d_ws;                             // 2,560,000
    int2*  erec  = (int2*)(A + (size_t)NB * CPAD * 128);     // 900,000 int2
    float* dinv  = (float*)(erec + (size_t)NB * ECAP);       // 20,000
    int*   gcur  = (int*)(dinv + N_NODES);                   // 625 (pad 640)
    float* fcT   = (float*)(gcur + 640);                     // 640,000
    float* lpart = fcT + (size_t)N_NODES * CPAD;             // 65,536

    float* degp = A;
    float* part = A;

    k0_init<<<1, 640, 0, stream>>>(gcur);
    k1_histscatter<<<2 * HBLKS + NSLAB, 512, 0, stream>>>(src, dst, ew, degp,
                                                          gcur, erec);
    k2_prep<<<NB, 256, 0, stream>>>(degp, fc_w, dinv, fcT);
    k3_foldgemm<<<NB, 512, 0, stream>>>(erec, gcur, dinv, fcT, x, part);
    k4_lred<<<dim3(N_CLASSES, NQ), 128, 0, stream>>>(part, lpart);
    k5_smax<<<1, 128, 0, stream>>>(lpart, fc_b, out);
}